// Round 1
// 276.603 us; speedup vs baseline: 1.0046x; 1.0046x over previous
//
#include <hip/hip_runtime.h>

#define N_SAMP 1024
#define XC_DIM 512
#define YC_DIM 256
#define HID_DIM 512

// ---------------------------------------------------------------------------
// K1: fused spatial pooling, coalesced + LDS transpose.
// __launch_bounds__(256,2) allows up to 256 VGPRs; previous rounds showed the
// compiler STILL interleaved load/ds_write pairs (VGPR_Count=32 -> each wave
// serialized 16 load latencies; 80.9us, VALUBusy 2%, 16% HBM). The
// sched_barrier(0) between the load loop and the store loop forbids that
// interleave: all 16 float4 loads issue back-to-back (64 VGPRs live), one
// vmcnt drain per wave instead of 16.
// ---------------------------------------------------------------------------
__global__ __launch_bounds__(256, 2) void pool_kernel(
    const float* __restrict__ x, const float* __restrict__ y,
    float* __restrict__ x_vec, float* __restrict__ y_vec) {
  __shared__ float s[256 * 17];
  const int t = threadIdx.x;
  const long blk = blockIdx.x;
  const float4* src;
  float* dst;
  long obase;
  if (blk < 2048) {            // x: 524288 outputs = 2048 blocks
    src = (const float4*)x; dst = x_vec; obase = blk * 256;
  } else {                     // y: 262144 outputs = 1024 blocks
    src = (const float4*)y; dst = y_vec; obase = (blk - 2048) * 256;
  }
  const float4* p = src + obase * 16;

  // Phase 1: issue all 16 coalesced loads back-to-back.
  float4 v[16];
#pragma unroll
  for (int k = 0; k < 16; ++k) v[k] = p[k * 256 + t];

  // Hard scheduling fence: nothing (in particular the ds_writes below) may be
  // moved above this point, so the register allocator must keep all 16 loads
  // in flight.
  __builtin_amdgcn_sched_barrier(0);

  // Phase 2: horizontal add + LDS transpose store.
#pragma unroll
  for (int k = 0; k < 16; ++k) {
    float sv = (v[k].x + v[k].y) + (v[k].z + v[k].w);
    const int o = k * 16 + (t >> 4);
    const int j = t & 15;
    s[o * 17 + j] = sv;
  }
  __syncthreads();
  float acc = 0.f;
#pragma unroll
  for (int j = 0; j < 16; ++j) acc += s[t * 17 + j];
  dst[obase + t] = acc * (1.0f / 64.0f);
}

// ---------------------------------------------------------------------------
// K2: Hp[s] = x_vec @ W1[k-chunk s]. 64x64 tile, 4x4/thread, BK=16,
// splitK=4 (chunk 128 = 8 iters) -> grid (8,16,4) = 512 blocks = 2/CU.
// ---------------------------------------------------------------------------
#define TBK 16

__global__ __launch_bounds__(256) void gemm1_kernel(
    const float* __restrict__ A, const float* __restrict__ B,
    float* __restrict__ Hp) {
  const int K = 512, Nn = 512;
  __shared__ float As[TBK][68];
  __shared__ float Bs[TBK][68];
  const int t = threadIdx.x;
  const int bn = blockIdx.x * 64;
  const int bm = blockIdx.y * 64;
  const int ks = blockIdx.z;          // 0..3, K-chunk of 128

  const int arow = t >> 2, acol = (t & 3) * 4;
  const int brow = t >> 4, bcol = (t & 15) * 4;
  const int row0 = (t >> 4) * 4, col0 = (t & 15) * 4;

  float acc[4][4] = {};
  const int k0 = ks * 128;

  float4 av = *(const float4*)&A[(bm + arow) * K + k0 + acol];
  float4 bv = *(const float4*)&B[(k0 + brow) * Nn + bn + bcol];

  for (int it = 0; it < 8; ++it) {
    __syncthreads();
    As[acol + 0][arow] = av.x;
    As[acol + 1][arow] = av.y;
    As[acol + 2][arow] = av.z;
    As[acol + 3][arow] = av.w;
    *(float4*)&Bs[brow][bcol] = bv;
    __syncthreads();
    if (it < 7) {
      const int k1 = k0 + (it + 1) * TBK;
      av = *(const float4*)&A[(bm + arow) * K + k1 + acol];
      bv = *(const float4*)&B[(k1 + brow) * Nn + bn + bcol];
    }
#pragma unroll
    for (int kk = 0; kk < TBK; ++kk) {
      float4 a = *(const float4*)&As[kk][row0];
      float4 b = *(const float4*)&Bs[kk][col0];
      acc[0][0] += a.x * b.x; acc[0][1] += a.x * b.y; acc[0][2] += a.x * b.z; acc[0][3] += a.x * b.w;
      acc[1][0] += a.y * b.x; acc[1][1] += a.y * b.y; acc[1][2] += a.y * b.z; acc[1][3] += a.y * b.w;
      acc[2][0] += a.z * b.x; acc[2][1] += a.z * b.y; acc[2][2] += a.z * b.z; acc[2][3] += a.z * b.w;
      acc[3][0] += a.w * b.x; acc[3][1] += a.w * b.y; acc[3][2] += a.w * b.z; acc[3][3] += a.w * b.w;
    }
  }

  float* H = Hp + (long)ks * (N_SAMP * HID_DIM);
#pragma unroll
  for (int i = 0; i < 4; ++i) {
    float4 o;
    o.x = acc[i][0]; o.y = acc[i][1]; o.z = acc[i][2]; o.w = acc[i][3];
    *(float4*)&H[(long)(bm + row0 + i) * Nn + bn + col0] = o;
  }
}

// ---------------------------------------------------------------------------
// K3: Mup[s] = relu(sum_{p=0..3} Hp[p] + b1) @ W2[k-chunk s].
// A built inline from the 4 gemm1 partials (h never materialized).
// splitK=8 -> grid (4,16,8) = 512 blocks.
// ---------------------------------------------------------------------------
__global__ __launch_bounds__(256) void gemm2_kernel(
    const float* __restrict__ Hp, const float* __restrict__ b1,
    const float* __restrict__ B, float* __restrict__ Mup) {
  const int K = 512, Nn = 256;
  __shared__ float As[TBK][68];
  __shared__ float Bs[TBK][68];
  const int t = threadIdx.x;
  const int bn = blockIdx.x * 64;
  const int bm = blockIdx.y * 64;
  const int ks = blockIdx.z;          // 0..7, K-chunk of 64
  const long HS = (long)N_SAMP * HID_DIM;

  const int arow = t >> 2, acol = (t & 3) * 4;
  const int brow = t >> 4, bcol = (t & 15) * 4;
  const int row0 = (t >> 4) * 4, col0 = (t & 15) * 4;

  float acc[4][4] = {};
  const int k0 = ks * 64;

  long aidx = (long)(bm + arow) * K + k0 + acol;
  float4 a0 = *(const float4*)&Hp[aidx];
  float4 a1 = *(const float4*)&Hp[aidx + HS];
  float4 a2 = *(const float4*)&Hp[aidx + 2 * HS];
  float4 a3 = *(const float4*)&Hp[aidx + 3 * HS];
  float4 bb = *(const float4*)&b1[k0 + acol];
  float4 bv = *(const float4*)&B[(k0 + brow) * Nn + bn + bcol];

  for (int it = 0; it < 4; ++it) {
    float4 av;
    av.x = fmaxf(a0.x + a1.x + a2.x + a3.x + bb.x, 0.0f);
    av.y = fmaxf(a0.y + a1.y + a2.y + a3.y + bb.y, 0.0f);
    av.z = fmaxf(a0.z + a1.z + a2.z + a3.z + bb.z, 0.0f);
    av.w = fmaxf(a0.w + a1.w + a2.w + a3.w + bb.w, 0.0f);
    __syncthreads();
    As[acol + 0][arow] = av.x;
    As[acol + 1][arow] = av.y;
    As[acol + 2][arow] = av.z;
    As[acol + 3][arow] = av.w;
    *(float4*)&Bs[brow][bcol] = bv;
    __syncthreads();
    if (it < 3) {
      const int k1 = k0 + (it + 1) * TBK;
      aidx = (long)(bm + arow) * K + k1 + acol;
      a0 = *(const float4*)&Hp[aidx];
      a1 = *(const float4*)&Hp[aidx + HS];
      a2 = *(const float4*)&Hp[aidx + 2 * HS];
      a3 = *(const float4*)&Hp[aidx + 3 * HS];
      bb = *(const float4*)&b1[k1 + acol];
      bv = *(const float4*)&B[(k1 + brow) * Nn + bn + bcol];
    }
#pragma unroll
    for (int kk = 0; kk < TBK; ++kk) {
      float4 a = *(const float4*)&As[kk][row0];
      float4 b = *(const float4*)&Bs[kk][col0];
      acc[0][0] += a.x * b.x; acc[0][1] += a.x * b.y; acc[0][2] += a.x * b.z; acc[0][3] += a.x * b.w;
      acc[1][0] += a.y * b.x; acc[1][1] += a.y * b.y; acc[1][2] += a.y * b.z; acc[1][3] += a.y * b.w;
      acc[2][0] += a.z * b.x; acc[2][1] += a.z * b.y; acc[2][2] += a.z * b.z; acc[2][3] += a.z * b.w;
      acc[3][0] += a.w * b.x; acc[3][1] += a.w * b.y; acc[3][2] += a.w * b.z; acc[3][3] += a.w * b.w;
    }
  }

  float* M = Mup + (long)ks * (N_SAMP * YC_DIM);
#pragma unroll
  for (int i = 0; i < 4; ++i) {
    float4 o;
    o.x = acc[i][0]; o.y = acc[i][1]; o.z = acc[i][2]; o.w = acc[i][3];
    *(float4*)&M[(long)(bm + row0 + i) * Nn + bn + col0] = o;
  }
}

// ---------------------------------------------------------------------------
// K4: fold mu = sum Mup + b2; accumulate dot(mu,y), colsum_mu, colsum_y.
// ---------------------------------------------------------------------------
__global__ __launch_bounds__(256) void reduce_kernel(
    const float* __restrict__ Mup, const float* __restrict__ b2,
    const float* __restrict__ yv, float* __restrict__ colsum_mu,
    float* __restrict__ colsum_y, float* __restrict__ dot_out) {
  const int d = threadIdx.x;
  const int n0 = blockIdx.x * 16;
  const long MS = (long)N_SAMP * YC_DIM;
  const float bb = b2[d];
  float cm = 0.f, cy = 0.f, dp = 0.f;
#pragma unroll 4
  for (int r = 0; r < 16; ++r) {
    const long idx = (long)(n0 + r) * YC_DIM + d;
    float mu = bb;
#pragma unroll
    for (int s = 0; s < 8; ++s) mu += Mup[idx + s * MS];
    const float yy = yv[idx];
    dp += mu * yy;
    cm += mu;
    cy += yy;
  }
  atomicAdd(&colsum_mu[d], cm);
  atomicAdd(&colsum_y[d], cy);
#pragma unroll
  for (int off = 1; off < 64; off <<= 1) dp += __shfl_xor(dp, off);
  if ((d & 63) == 0) atomicAdd(dot_out, dp);
}

// ---------------------------------------------------------------------------
// K5: out = dot/N - (1/N^2) * sum_d colsum_y[d]*colsum_mu[d]
// ---------------------------------------------------------------------------
__global__ __launch_bounds__(256) void finalize_kernel(
    const float* __restrict__ colsum_mu, const float* __restrict__ colsum_y,
    const float* __restrict__ dot_in, float* __restrict__ out) {
  __shared__ float partial[4];
  const int t = threadIdx.x;
  float v = colsum_mu[t] * colsum_y[t];
#pragma unroll
  for (int off = 1; off < 64; off <<= 1) v += __shfl_xor(v, off);
  if ((t & 63) == 0) partial[t >> 6] = v;
  __syncthreads();
  if (t == 0) {
    float tot = partial[0] + partial[1] + partial[2] + partial[3];
    out[0] = dot_in[0] * (1.0f / 1024.0f) - tot * (1.0f / (1024.0f * 1024.0f));
  }
}

// ---------------------------------------------------------------------------
extern "C" void kernel_launch(void* const* d_in, const int* in_sizes, int n_in,
                              void* d_out, int out_size, void* d_ws, size_t ws_size,
                              hipStream_t stream) {
  const float* x  = (const float*)d_in[0];
  const float* y  = (const float*)d_in[1];
  const float* W1 = (const float*)d_in[2];
  const float* b1 = (const float*)d_in[3];
  const float* W2 = (const float*)d_in[4];
  const float* b2 = (const float*)d_in[5];
  float* out = (float*)d_out;

  char* ws = (char*)d_ws;
  float* x_vec = (float*)ws;                    // 2 MB
  float* y_vec = (float*)(ws + (2lu << 20));    // 1 MB
  float* Hp    = (float*)(ws + (4lu << 20));    // 4 x 2 MB = 8 MB
  float* Mup   = (float*)(ws + (12lu << 20));   // 8 x 1 MB = 8 MB
  float* accum = (float*)(ws + (20lu << 20));
  float* colsum_mu = accum;
  float* colsum_y  = accum + 256;
  float* dotp      = accum + 512;

  hipMemsetAsync(accum, 0, 513 * sizeof(float), stream);

  pool_kernel<<<3072, 256, 0, stream>>>(x, y, x_vec, y_vec);

  gemm1_kernel<<<dim3(8, 16, 4), 256, 0, stream>>>(x_vec, W1, Hp);

  gemm2_kernel<<<dim3(4, 16, 8), 256, 0, stream>>>(Hp, b1, W2, Mup);

  reduce_kernel<<<64, 256, 0, stream>>>(Mup, b2, y_vec, colsum_mu,
                                        colsum_y, dotp);

  finalize_kernel<<<1, 256, 0, stream>>>(colsum_mu, colsum_y, dotp, out);
}